// Round 11
// baseline (1992.847 us; speedup 1.0000x reference)
//
#include <hip/hip_runtime.h>

#define NB 16
#define WD 17
#define NPIX 289
#define PWD 19
#define PPIX 361   // 19*19 zero-padded
#define FWD 21
#define FPIX 441   // 21*21 zero-padded food
#define NT 512     // 8 waves, 2/SIMD; every wave: 37 pixels + 8 hidden units

typedef float v2f __attribute__((ext_vector_type(2)));
typedef float v4f __attribute__((ext_vector_type(4)));

__device__ __forceinline__ v2f vfma2(v2f a, v2f b, v2f c) {
  return __builtin_elementwise_fma(a, b, c);
}
__device__ __forceinline__ float fmax3(float a, float b, float c) {
  return fmaxf(fmaxf(a, b), c);   // fuses to v_max3_f32
}

__global__ __launch_bounds__(NT)
__attribute__((amdgpu_waves_per_eu(2, 2)))
void ca_kernel(
    const float* __restrict__ cell_in, const float* __restrict__ food_in,
    const int* __restrict__ steps_in,
    const float* __restrict__ fc1_w, const float* __restrict__ fc1_b,
    const float* __restrict__ fc2_w, const float* __restrict__ fc2_b,
    float* __restrict__ out)
{
  __shared__ v4f   s_cellv[PPIX];                // (ch0,ch1,ch2,scent); ch0 PRE-keep
  __shared__ float s_x0[PPIX];                   // pre-mask x0 plane (borders 0)
  __shared__ __align__(16) float s_v[320];       // clipped x0; [289..320)=0 pads
  __shared__ v4f   s_y0[320], s_y1[320], s_y2[320];
  __shared__ v4f   s_pd[8][320];                 // per-wave partial deltas
  __shared__ float s_food[FPIX];
  __shared__ float s_w[1088];                    // fc1_w 768 | fc1_b 64 | fc2_w 256
  __shared__ unsigned s_kcnt[2];                 // living count, ping-pong by step
  __shared__ float s_sum[8];

  const int b    = blockIdx.x;
  const int tid  = threadIdx.x;
  const int lane = tid & 63;
  const int wv   = tid >> 6;
  // Spread mapping: 37 pixels/wave -> balanced issue across all 4 SIMDs.
  const int p    = wv * 37 + lane;
  const bool act = (lane < 37) && (p < NPIX);
  const int pv   = act ? p : 0;
  const int py   = pv / WD, px = pv - py * WD;
  const int pp   = (py + 1) * PWD + px + 1;
  const int fp   = (py + 2) * FWD + px + 2;

  // ---------------- init ----------------
  for (int i = tid; i < PPIX; i += NT) { v4f z = {0.f,0.f,0.f,0.f}; s_cellv[i]=z; }
  for (int i = tid; i < PPIX; i += NT) s_x0[i] = 0.f;
  for (int i = tid; i < 320;  i += NT) s_v[i] = 0.f;
  for (int i = tid; i < FPIX; i += NT) s_food[i] = 0.f;
  for (int i = tid; i < 768;  i += NT) s_w[i] = fc1_w[i];
  for (int i = tid; i < 64;   i += NT) s_w[768 + i] = fc1_b[i];
  for (int i = tid; i < 256;  i += NT) s_w[832 + i] = fc2_w[i];
  if (tid == 0) { s_kcnt[0] = 0u; s_kcnt[1] = 0u; }
  __syncthreads();

  float o0 = 0.f, o1 = 0.f, o2 = 0.f, o3 = 0.f;
  if (act) {
    const float* cb = cell_in + (size_t)b * (4 * NPIX);
    o0 = cb[p]; o1 = cb[NPIX + p]; o2 = cb[2 * NPIX + p]; o3 = cb[3 * NPIX + p];
    s_food[fp] = food_in[(size_t)b * NPIX + p];
  }
  __syncthreads();

  // weights -> VGPRs from LDS (wave wv owns hidden units [8wv, 8wv+8))
  // r9 lesson: 16 units/wave (~272 regs) spills to scratch (17ms). 8 is max.
  const int h0 = wv * 8;
  v2f w1p[8][6], b1v[8], w2p01[8], w2p23[8];
  #pragma unroll
  for (int j = 0; j < 8; ++j) {
    const int h = h0 + j;
    #pragma unroll
    for (int dd = 0; dd < 6; ++dd) {
      v2f w; w.x = s_w[h * 12 + 2 * dd]; w.y = s_w[h * 12 + 2 * dd + 1];
      w1p[j][dd] = w;
    }
    v2f bb; bb.x = s_w[768 + h]; bb.y = 0.f; b1v[j] = bb;
    v2f wa; wa.x = s_w[832 + 0 * 64 + h]; wa.y = s_w[832 + 1 * 64 + h]; w2p01[j] = wa;
    v2f wb; wb.x = s_w[832 + 2 * 64 + h]; wb.y = s_w[832 + 3 * 64 + h]; w2p23[j] = wb;
  }
  // Pin weights in registers: opaque asm is the new def, so the compiler
  // cannot rematerialize from LDS inside B (r4: -25%, AGPR-stash on gfx950).
  #pragma unroll
  for (int j = 0; j < 8; ++j) {
    #pragma unroll
    for (int dd = 0; dd < 6; ++dd) asm volatile("" : "+v"(w1p[j][dd]));
    asm volatile("" : "+v"(b1v[j]));
    asm volatile("" : "+v"(w2p01[j]));
    asm volatile("" : "+v"(w2p23[j]));
  }
  const float b20 = fc2_b[0], b21 = fc2_b[1], b22 = fc2_b[2], b23 = fc2_b[3];

  // scent = conv5x5(food), constant; stage into s_x0 to get its Sobel
  float scent = 0.f;
  if (act) {
    const float w5[5][5] = {
      {0.f,0.125f,0.25f,0.125f,0.f},
      {0.125f,0.25f,0.5f,0.25f,0.125f},
      {0.25f,0.5f,1.0f,0.5f,0.25f},
      {0.125f,0.25f,0.5f,0.25f,0.125f},
      {0.f,0.125f,0.25f,0.125f,0.f}};
    #pragma unroll
    for (int ky = 0; ky < 5; ++ky)
      #pragma unroll
      for (int kx = 0; kx < 5; ++kx)
        if (w5[ky][kx] != 0.f)
          scent = fmaf(w5[ky][kx], s_food[fp + (ky - 2) * FWD + kx - 2], scent);
    s_x0[pp] = scent;
    v4f cv; cv.x = o0; cv.y = o1; cv.z = o2; cv.w = scent;
    s_cellv[pp] = cv;
  }
  __syncthreads();

  float dxs = 0.f, dys = 0.f;
  if (act) {
    const int q = pp;
    float t00=s_x0[q-PWD-1], t01=s_x0[q-PWD], t02=s_x0[q-PWD+1];
    float t10=s_x0[q-1],                      t12=s_x0[q+1];
    float t20=s_x0[q+PWD-1], t21=s_x0[q+PWD], t22=s_x0[q+PWD+1];
    dxs = ((t02-t00)+2.f*(t12-t10)+(t22-t20))*0.125f;
    dys = ((t20-t00)+2.f*(t21-t01)+(t22-t02))*0.125f;
  }
  {
    unsigned long long m = __ballot(act && (o0 > 0.1f));
    if (lane == 0) atomicAdd(&s_kcnt[0], (unsigned)__popcll(m));
  }
  __syncthreads();

  const int steps = steps_in[0];
  float x0 = 0.f, x1 = 0.f, x2 = 0.f, x3 = 0.f;
  bool pre = false;
  unsigned kth = 0u;   // step-0 update sees the raw initial cell (keep-all)

  // prologue prefetch of step-0 stencil neighborhood (s_cellv final here)
  v4f n00, n01, n02, n10, n12, n20, n21, n22;
  {
    v4f z = {0.f,0.f,0.f,0.f};
    n00=n01=n02=n10=n12=n20=n21=n22=z;
  }
  if (act) {
    const int q = pp;
    n00 = s_cellv[q-PWD-1]; n01 = s_cellv[q-PWD]; n02 = s_cellv[q-PWD+1];
    n10 = s_cellv[q-1];                           n12 = s_cellv[q+1];
    n20 = s_cellv[q+PWD-1]; n21 = s_cellv[q+PWD]; n22 = s_cellv[q+PWD+1];
  }

  for (int s = 0; s < steps; ++s) {
    // ---- A: stencil on PREFETCHED neighbors; ch0 masked inline by kth ----
    if (act) {
      v4f m00=n00, m01=n01, m02=n02, m10=n10, m12=n12, m20=n20, m21=n21, m22=n22;
      m00.x = (__float_as_uint(m00.x) >= kth) ? m00.x : 0.f;
      m01.x = (__float_as_uint(m01.x) >= kth) ? m01.x : 0.f;
      m02.x = (__float_as_uint(m02.x) >= kth) ? m02.x : 0.f;
      m10.x = (__float_as_uint(m10.x) >= kth) ? m10.x : 0.f;
      m12.x = (__float_as_uint(m12.x) >= kth) ? m12.x : 0.f;
      m20.x = (__float_as_uint(m20.x) >= kth) ? m20.x : 0.f;
      m21.x = (__float_as_uint(m21.x) >= kth) ? m21.x : 0.f;
      m22.x = (__float_as_uint(m22.x) >= kth) ? m22.x : 0.f;
      float mx = fmax3(fmax3(m00.x, m01.x, m02.x),
                       fmax3(m10.x, o0,    m12.x),
                       fmax3(m20.x, m21.x, m22.x));
      pre = mx > 0.1f;
      v4f q0; q0.x=o0; q0.y=o1; q0.z=o2; q0.w=scent;
      // packed Sobel over all 4 comps (w lane recomputed then overwritten)
      v4f dx4 = ((m02 - m00) + 2.f*(m12 - m10) + (m22 - m20)) * 0.125f;
      v4f dy4 = ((m20 - m00) + 2.f*(m21 - m01) + (m22 - m02)) * 0.125f;
      dx4.w = dxs;
      dy4.w = dys;
      s_y0[p] = q0; s_y1[p] = dx4; s_y2[p] = dy4;
    }
    __syncthreads();

    // ---- B: fully unrolled, 2-deep pipelined (no spill: 6 v4f in flight;
    //      r8's 15-deep batch spilled -> WRITE_SIZE 508KB of scratch) ----
    {
      auto mlp8 = [&](const v4f& c0, const v4f& c1, const v4f& c2,
                      int qx, bool st) {
        v2f y01; y01.x=c0.x; y01.y=c0.y;
        v2f y23; y23.x=c0.z; y23.y=c0.w;
        v2f y45; y45.x=c1.x; y45.y=c1.y;
        v2f y67; y67.x=c1.z; y67.y=c1.w;
        v2f y89; y89.x=c2.x; y89.y=c2.y;
        v2f yab; yab.x=c2.z; yab.y=c2.w;
        v2f acc01; acc01.x = 0.f; acc01.y = 0.f;
        v2f acc23; acc23.x = 0.f; acc23.y = 0.f;
        #pragma unroll
        for (int j = 0; j < 8; ++j) {
          v2f a = b1v[j];
          a = vfma2(w1p[j][0], y01, a);
          a = vfma2(w1p[j][1], y23, a);
          a = vfma2(w1p[j][2], y45, a);
          a = vfma2(w1p[j][3], y67, a);
          a = vfma2(w1p[j][4], y89, a);
          a = vfma2(w1p[j][5], yab, a);
          float g = fmaxf(a.x + a.y, 0.f);
          v2f gg; gg.x = g; gg.y = g;
          acc01 = vfma2(w2p01[j], gg, acc01);
          acc23 = vfma2(w2p23[j], gg, acc23);
        }
        if (st) {
          v4f r; r.x=acc01.x; r.y=acc01.y; r.z=acc23.x; r.w=acc23.y;
          s_pd[wv][qx] = r;
        }
      };
      v4f a0 = s_y0[lane], a1 = s_y1[lane], a2 = s_y2[lane];
      v4f b0 = s_y0[64 + lane], b1 = s_y1[64 + lane], b2 = s_y2[64 + lane];
      mlp8(a0, a1, a2, lane, true);
      a0 = s_y0[128 + lane]; a1 = s_y1[128 + lane]; a2 = s_y2[128 + lane];
      mlp8(b0, b1, b2, 64 + lane, true);
      b0 = s_y0[192 + lane]; b1 = s_y1[192 + lane]; b2 = s_y2[192 + lane];
      mlp8(a0, a1, a2, 128 + lane, true);
      a0 = s_y0[256 + lane]; a1 = s_y1[256 + lane]; a2 = s_y2[256 + lane];
      mlp8(b0, b1, b2, 192 + lane, true);
      mlp8(a0, a1, a2, 256 + lane, lane < 33);   // 256+lane < 289
    }
    __syncthreads();

    // ---- C: sum 8 partials, explicit 2-level tree -> x; stage x0 plane ----
    if (act) {
      v4f t0 = s_pd[0][p] + s_pd[1][p];
      v4f t1 = s_pd[2][p] + s_pd[3][p];
      v4f t2 = s_pd[4][p] + s_pd[5][p];
      v4f t3 = s_pd[6][p] + s_pd[7][p];
      v4f d = (t0 + t1) + (t2 + t3);
      x0 = o0 + d.x + b20; x1 = o1 + d.y + b21;
      x2 = o2 + d.z + b22; x3 = scent + d.w + b23;
      s_x0[pp] = x0;
    }
    __syncthreads();

    // zero the counter slot F will accumulate into (old value's only consumer
    // was E of step s-1); issued early, fenced by the barrier below
    if (tid == 63) s_kcnt[(s + 1) & 1] = 0u;

    // ---- D: post-mask maxpool, clip, stage s_v + cell v4f (ch0 pre-keep) ----
    if (act) {
      const int q = pp;
      float m0 = fmax3(fmax3(s_x0[q-PWD-1], s_x0[q-PWD], s_x0[q-PWD+1]),
                       fmax3(s_x0[q-1],     x0,          s_x0[q+1]),
                       fmax3(s_x0[q+PWD-1], s_x0[q+PWD], s_x0[q+PWD+1]));
      bool km = pre && (m0 > 0.1f);
      o0 = km ? fminf(fmaxf(x0,   0.f),  1.f) : 0.f;  // clip[-10,10] then [0,1] == [0,1]
      o1 = km ? fminf(fmaxf(x1, -10.f), 10.f) : 0.f;
      o2 = km ? fminf(fmaxf(x2, -10.f), 10.f) : 0.f;
      o3 = km ? fminf(fmaxf(x3, -10.f), 10.f) : 0.f;
      s_v[p] = o0;
      v4f cv; cv.x = o0; cv.y = o1; cv.z = o2; cv.w = scent;
      s_cellv[pp] = cv;
    }
    __syncthreads();

    // ---- E inputs first (earliest waits), then next-A prefetch ----
    const unsigned kc_u = s_kcnt[s & 1];                   // running count
    const uint4 va = ((const uint4*)s_v)[lane];            // 0..255
    const unsigned vb = ((const unsigned*)s_v)[256 + lane];// 256..319 (pads 0)
    if (act) {
      const int q = pp;
      n00 = s_cellv[q-PWD-1]; n01 = s_cellv[q-PWD]; n02 = s_cellv[q-PWD+1];
      n10 = s_cellv[q-1];                           n12 = s_cellv[q+1];
      n20 = s_cellv[q+PWD-1]; n21 = s_cellv[q+PWD]; n22 = s_cellv[q+PWD+1];
    }

    // ---- E (every wave, redundant): warm-probe + probe-bounded radix ----
    // r6 lesson: true kth can be ANY value in [0,1] incl. 0 -> radix spans
    // bits 29..0 from t=0. NEW: on probe miss, monotonicity of count_ge vs
    // cp=count_ge(kprev) gives free accept/reject for candidates on the
    // known side of kprev (one SALU compare replaces 5 ballots).
    {
      #define CNT5(cand) ((unsigned)__popcll(__ballot(va.x >= (cand))) \
                        + (unsigned)__popcll(__ballot(va.y >= (cand))) \
                        + (unsigned)__popcll(__ballot(va.z >= (cand))) \
                        + (unsigned)__popcll(__ballot(va.w >= (cand))) \
                        + (unsigned)__popcll(__ballot(vb   >= (cand))))
      int kc = (int)kc_u;
      int k_idx = kc - 1; if (k_idx < 0) k_idx += NPIX;  // torch wrap
      if (k_idx >= NPIX - 1) {
        kth = 0u;                       // keep-all
      } else {
        const unsigned k = (unsigned)(k_idx + 1);
        bool done = false;
        unsigned kprev = kth;
        bool up = false;                // miss direction: kth >= kprev?
        // Warm-start probe: if count_ge(kprev) == k, {v>=kprev} is an
        // upward-closed set of exactly k values == the top-k set (ties would
        // make the count exceed k). Skip when kprev==0 (pads would count).
        if (kprev != 0u) {
          unsigned cp = CNT5(kprev);
          if (cp == k) done = true;     // keep kth as-is
          else up = (cp > k);           // cp>k: kth>=kprev; cp<k: kth<kprev
        } else {
          kprev = 0xFFFFFFFFu;          // sentinel: no bound info, up=false
        }
        if (!done) {
          unsigned t = 0;
          #pragma unroll 1
          for (int bit = 29; bit >= 0; --bit) {
            unsigned cand = t | (1u << bit);
            if (up) {
              // kth >= kprev: cand <= kprev => count_ge(cand) >= cp > k
              if (cand <= kprev) { t = cand; continue; }   // free accept
            } else {
              // kth < kprev: cand >= kprev => count_ge(cand) <= cp < k
              if (cand >= kprev) continue;                 // free reject
            }
            unsigned c = CNT5(cand);
            if (c >= k) t = cand;   // largest x with count_ge(x) >= k
            // Early exit: count_ge(cand)==k => exact top-k set. Uniform.
            if (c == k) break;
          }
          kth = t;
        }
      }
      #undef CNT5
      // F (registers only): apply keep to own o0, publish living count
      bool alive = false;
      if (act) {
        if (__float_as_uint(o0) < kth) o0 = 0.f;  // nonneg: uint cmp == float cmp
        alive = o0 > 0.1f;
      }
      unsigned long long m = __ballot(alive);
      if (lane == 0) atomicAdd(&s_kcnt[(s + 1) & 1], (unsigned)__popcll(m));
      // no barrier: next-A uses prefetched regs + reg kth; s_kcnt read in
      // next-E is fenced by barriers b1..b4.
    }
  }

  // ---- outputs: cell | food | total_pixel_val | living_count ----
  if (act) {
    float* oc = out + (size_t)b * (4 * NPIX);
    oc[p] = o0; oc[NPIX + p] = o1; oc[2*NPIX + p] = o2; oc[3*NPIX + p] = o3;
    out[NB*4*NPIX + (size_t)b * NPIX + p] = food_in[(size_t)b * NPIX + p];
  }
  float sv = act ? o0 : 0.f;
  #pragma unroll
  for (int off = 32; off > 0; off >>= 1) sv += __shfl_down(sv, off, 64);
  if (lane == 0) s_sum[wv] = sv;
  __syncthreads();
  if (tid == 0) {
    float tot = 0.f;
    #pragma unroll
    for (int w = 0; w < 8; ++w) tot += s_sum[w];
    out[NB*4*NPIX + NB*NPIX + b]      = tot;
    out[NB*4*NPIX + NB*NPIX + NB + b] = (float)s_kcnt[steps & 1];
  }
}

extern "C" void kernel_launch(void* const* d_in, const int* in_sizes, int n_in,
                              void* d_out, int out_size, void* d_ws, size_t ws_size,
                              hipStream_t stream) {
  (void)in_sizes; (void)n_in; (void)d_ws; (void)ws_size; (void)out_size;
  ca_kernel<<<dim3(NB), dim3(NT), 0, stream>>>(
      (const float*)d_in[0], (const float*)d_in[1], (const int*)d_in[2],
      (const float*)d_in[3], (const float*)d_in[4], (const float*)d_in[5],
      (const float*)d_in[6], (float*)d_out);
}

// Round 12
// 1789.263 us; speedup vs baseline: 1.1138x; 1.1138x over previous
//
#include <hip/hip_runtime.h>

#define NB 16
#define WD 17
#define NPIX 289
#define PWD 19
#define PPIX 361   // 19*19 zero-padded
#define FWD 21
#define FPIX 441   // 21*21 zero-padded food
#define NT 512     // 8 waves, 2/SIMD; every wave: 37 pixels + 8 hidden units

typedef float v2f __attribute__((ext_vector_type(2)));
typedef float v4f __attribute__((ext_vector_type(4)));

__device__ __forceinline__ v2f vfma2(v2f a, v2f b, v2f c) {
  return __builtin_elementwise_fma(a, b, c);
}
__device__ __forceinline__ float fmax3(float a, float b, float c) {
  return fmaxf(fmaxf(a, b), c);   // fuses to v_max3_f32
}

__global__ __launch_bounds__(NT)
__attribute__((amdgpu_waves_per_eu(2, 2)))
void ca_kernel(
    const float* __restrict__ cell_in, const float* __restrict__ food_in,
    const int* __restrict__ steps_in,
    const float* __restrict__ fc1_w, const float* __restrict__ fc1_b,
    const float* __restrict__ fc2_w, const float* __restrict__ fc2_b,
    float* __restrict__ out)
{
  __shared__ v4f   s_cellv[PPIX];                // (ch0,ch1,ch2,scent); ch0 PRE-keep
  __shared__ float s_x0[PPIX];                   // pre-mask x0 plane (borders 0)
  __shared__ __align__(16) float s_v[320];       // clipped x0; [289..320)=0 pads
  __shared__ v4f   s_y0[320], s_y1[320], s_y2[320];
  __shared__ v4f   s_pd[8][320];                 // per-wave partial deltas
  __shared__ float s_food[FPIX];
  __shared__ float s_w[1088];                    // fc1_w 768 | fc1_b 64 | fc2_w 256
  __shared__ unsigned s_kcnt[2];                 // living count, ping-pong by step
  __shared__ float s_sum[8];

  const int b    = blockIdx.x;
  const int tid  = threadIdx.x;
  const int lane = tid & 63;
  const int wv   = tid >> 6;
  // Spread mapping: 37 pixels/wave -> balanced issue across all 4 SIMDs.
  const int p    = wv * 37 + lane;
  const bool act = (lane < 37) && (p < NPIX);
  const int pv   = act ? p : 0;
  const int py   = pv / WD, px = pv - py * WD;
  const int pp   = (py + 1) * PWD + px + 1;
  const int fp   = (py + 2) * FWD + px + 2;

  // ---------------- init ----------------
  for (int i = tid; i < PPIX; i += NT) { v4f z = {0.f,0.f,0.f,0.f}; s_cellv[i]=z; }
  for (int i = tid; i < PPIX; i += NT) s_x0[i] = 0.f;
  for (int i = tid; i < 320;  i += NT) s_v[i] = 0.f;
  for (int i = tid; i < FPIX; i += NT) s_food[i] = 0.f;
  for (int i = tid; i < 768;  i += NT) s_w[i] = fc1_w[i];
  for (int i = tid; i < 64;   i += NT) s_w[768 + i] = fc1_b[i];
  for (int i = tid; i < 256;  i += NT) s_w[832 + i] = fc2_w[i];
  if (tid == 0) { s_kcnt[0] = 0u; s_kcnt[1] = 0u; }
  __syncthreads();

  float o0 = 0.f, o1 = 0.f, o2 = 0.f, o3 = 0.f;
  if (act) {
    const float* cb = cell_in + (size_t)b * (4 * NPIX);
    o0 = cb[p]; o1 = cb[NPIX + p]; o2 = cb[2 * NPIX + p]; o3 = cb[3 * NPIX + p];
    s_food[fp] = food_in[(size_t)b * NPIX + p];
  }
  __syncthreads();

  // weights -> VGPRs from LDS (wave wv owns hidden units [8wv, 8wv+8))
  // r9 lesson: 16 units/wave (~272 regs) spills to scratch (17ms). 8 is max.
  const int h0 = wv * 8;
  v2f w1p[8][6], b1v[8], w2p01[8], w2p23[8];
  #pragma unroll
  for (int j = 0; j < 8; ++j) {
    const int h = h0 + j;
    #pragma unroll
    for (int dd = 0; dd < 6; ++dd) {
      v2f w; w.x = s_w[h * 12 + 2 * dd]; w.y = s_w[h * 12 + 2 * dd + 1];
      w1p[j][dd] = w;
    }
    v2f bb; bb.x = s_w[768 + h]; bb.y = 0.f; b1v[j] = bb;
    v2f wa; wa.x = s_w[832 + 0 * 64 + h]; wa.y = s_w[832 + 1 * 64 + h]; w2p01[j] = wa;
    v2f wb; wb.x = s_w[832 + 2 * 64 + h]; wb.y = s_w[832 + 3 * 64 + h]; w2p23[j] = wb;
  }
  // Pin weights in registers: opaque asm is the new def, so the compiler
  // cannot rematerialize from LDS inside B (r4: -25%, AGPR-stash on gfx950).
  #pragma unroll
  for (int j = 0; j < 8; ++j) {
    #pragma unroll
    for (int dd = 0; dd < 6; ++dd) asm volatile("" : "+v"(w1p[j][dd]));
    asm volatile("" : "+v"(b1v[j]));
    asm volatile("" : "+v"(w2p01[j]));
    asm volatile("" : "+v"(w2p23[j]));
  }
  const float b20 = fc2_b[0], b21 = fc2_b[1], b22 = fc2_b[2], b23 = fc2_b[3];

  // scent = conv5x5(food), constant; stage into s_x0 to get its Sobel
  float scent = 0.f;
  if (act) {
    const float w5[5][5] = {
      {0.f,0.125f,0.25f,0.125f,0.f},
      {0.125f,0.25f,0.5f,0.25f,0.125f},
      {0.25f,0.5f,1.0f,0.5f,0.25f},
      {0.125f,0.25f,0.5f,0.25f,0.125f},
      {0.f,0.125f,0.25f,0.125f,0.f}};
    #pragma unroll
    for (int ky = 0; ky < 5; ++ky)
      #pragma unroll
      for (int kx = 0; kx < 5; ++kx)
        if (w5[ky][kx] != 0.f)
          scent = fmaf(w5[ky][kx], s_food[fp + (ky - 2) * FWD + kx - 2], scent);
    s_x0[pp] = scent;
    v4f cv; cv.x = o0; cv.y = o1; cv.z = o2; cv.w = scent;
    s_cellv[pp] = cv;
  }
  __syncthreads();

  float dxs = 0.f, dys = 0.f;
  if (act) {
    const int q = pp;
    float t00=s_x0[q-PWD-1], t01=s_x0[q-PWD], t02=s_x0[q-PWD+1];
    float t10=s_x0[q-1],                      t12=s_x0[q+1];
    float t20=s_x0[q+PWD-1], t21=s_x0[q+PWD], t22=s_x0[q+PWD+1];
    dxs = ((t02-t00)+2.f*(t12-t10)+(t22-t20))*0.125f;
    dys = ((t20-t00)+2.f*(t21-t01)+(t22-t02))*0.125f;
  }
  {
    unsigned long long m = __ballot(act && (o0 > 0.1f));
    if (lane == 0) atomicAdd(&s_kcnt[0], (unsigned)__popcll(m));
  }
  __syncthreads();

  const int steps = steps_in[0];
  float x0 = 0.f, x1 = 0.f, x2 = 0.f, x3 = 0.f;
  bool pre = false;
  unsigned kth = 0u;   // step-0 update sees the raw initial cell (keep-all)

  // prologue prefetch of step-0 stencil neighborhood (s_cellv final here)
  v4f n00, n01, n02, n10, n12, n20, n21, n22;
  {
    v4f z = {0.f,0.f,0.f,0.f};
    n00=n01=n02=n10=n12=n20=n21=n22=z;
  }
  if (act) {
    const int q = pp;
    n00 = s_cellv[q-PWD-1]; n01 = s_cellv[q-PWD]; n02 = s_cellv[q-PWD+1];
    n10 = s_cellv[q-1];                           n12 = s_cellv[q+1];
    n20 = s_cellv[q+PWD-1]; n21 = s_cellv[q+PWD]; n22 = s_cellv[q+PWD+1];
  }

  for (int s = 0; s < steps; ++s) {
    // ---- A: stencil on PREFETCHED neighbors; ch0 masked inline by kth ----
    if (act) {
      v4f m00=n00, m01=n01, m02=n02, m10=n10, m12=n12, m20=n20, m21=n21, m22=n22;
      m00.x = (__float_as_uint(m00.x) >= kth) ? m00.x : 0.f;
      m01.x = (__float_as_uint(m01.x) >= kth) ? m01.x : 0.f;
      m02.x = (__float_as_uint(m02.x) >= kth) ? m02.x : 0.f;
      m10.x = (__float_as_uint(m10.x) >= kth) ? m10.x : 0.f;
      m12.x = (__float_as_uint(m12.x) >= kth) ? m12.x : 0.f;
      m20.x = (__float_as_uint(m20.x) >= kth) ? m20.x : 0.f;
      m21.x = (__float_as_uint(m21.x) >= kth) ? m21.x : 0.f;
      m22.x = (__float_as_uint(m22.x) >= kth) ? m22.x : 0.f;
      float mx = fmax3(fmax3(m00.x, m01.x, m02.x),
                       fmax3(m10.x, o0,    m12.x),
                       fmax3(m20.x, m21.x, m22.x));
      pre = mx > 0.1f;
      v4f q0; q0.x=o0; q0.y=o1; q0.z=o2; q0.w=scent;
      // packed Sobel over all 4 comps (w lane recomputed then overwritten)
      v4f dx4 = ((m02 - m00) + 2.f*(m12 - m10) + (m22 - m20)) * 0.125f;
      v4f dy4 = ((m20 - m00) + 2.f*(m21 - m01) + (m22 - m02)) * 0.125f;
      dx4.w = dxs;
      dy4.w = dys;
      s_y0[p] = q0; s_y1[p] = dx4; s_y2[p] = dy4;
    }
    __syncthreads();

    // ---- B: fully unrolled, 2-deep pipelined (no spill: 6 v4f in flight;
    //      r8's 15-deep batch spilled -> WRITE_SIZE 508KB of scratch) ----
    {
      auto mlp8 = [&](const v4f& c0, const v4f& c1, const v4f& c2,
                      int qx, bool st) {
        v2f y01; y01.x=c0.x; y01.y=c0.y;
        v2f y23; y23.x=c0.z; y23.y=c0.w;
        v2f y45; y45.x=c1.x; y45.y=c1.y;
        v2f y67; y67.x=c1.z; y67.y=c1.w;
        v2f y89; y89.x=c2.x; y89.y=c2.y;
        v2f yab; yab.x=c2.z; yab.y=c2.w;
        v2f acc01; acc01.x = 0.f; acc01.y = 0.f;
        v2f acc23; acc23.x = 0.f; acc23.y = 0.f;
        #pragma unroll
        for (int j = 0; j < 8; ++j) {
          v2f a = b1v[j];
          a = vfma2(w1p[j][0], y01, a);
          a = vfma2(w1p[j][1], y23, a);
          a = vfma2(w1p[j][2], y45, a);
          a = vfma2(w1p[j][3], y67, a);
          a = vfma2(w1p[j][4], y89, a);
          a = vfma2(w1p[j][5], yab, a);
          float g = fmaxf(a.x + a.y, 0.f);
          v2f gg; gg.x = g; gg.y = g;
          acc01 = vfma2(w2p01[j], gg, acc01);
          acc23 = vfma2(w2p23[j], gg, acc23);
        }
        if (st) {
          v4f r; r.x=acc01.x; r.y=acc01.y; r.z=acc23.x; r.w=acc23.y;
          s_pd[wv][qx] = r;
        }
      };
      v4f a0 = s_y0[lane], a1 = s_y1[lane], a2 = s_y2[lane];
      v4f b0 = s_y0[64 + lane], b1 = s_y1[64 + lane], b2 = s_y2[64 + lane];
      mlp8(a0, a1, a2, lane, true);
      a0 = s_y0[128 + lane]; a1 = s_y1[128 + lane]; a2 = s_y2[128 + lane];
      mlp8(b0, b1, b2, 64 + lane, true);
      b0 = s_y0[192 + lane]; b1 = s_y1[192 + lane]; b2 = s_y2[192 + lane];
      mlp8(a0, a1, a2, 128 + lane, true);
      a0 = s_y0[256 + lane]; a1 = s_y1[256 + lane]; a2 = s_y2[256 + lane];
      mlp8(b0, b1, b2, 192 + lane, true);
      mlp8(a0, a1, a2, 256 + lane, lane < 33);   // 256+lane < 289
    }
    __syncthreads();

    // ---- C: sum 8 partials (packed adds) -> x; stage x0 plane ----
    if (act) {
      v4f d = s_pd[0][p];
      #pragma unroll
      for (int w = 1; w < 8; ++w) d += s_pd[w][p];
      x0 = o0 + d.x + b20; x1 = o1 + d.y + b21;
      x2 = o2 + d.z + b22; x3 = scent + d.w + b23;
      s_x0[pp] = x0;
    }
    __syncthreads();

    // zero the counter slot F will accumulate into (old value's only consumer
    // was E of step s-1); issued early, fenced by the barrier below
    if (tid == 63) s_kcnt[(s + 1) & 1] = 0u;

    // ---- D: post-mask maxpool, clip, stage s_v + cell v4f (ch0 pre-keep) ----
    if (act) {
      const int q = pp;
      float m0 = fmax3(fmax3(s_x0[q-PWD-1], s_x0[q-PWD], s_x0[q-PWD+1]),
                       fmax3(s_x0[q-1],     x0,          s_x0[q+1]),
                       fmax3(s_x0[q+PWD-1], s_x0[q+PWD], s_x0[q+PWD+1]));
      bool km = pre && (m0 > 0.1f);
      o0 = km ? fminf(fmaxf(x0,   0.f),  1.f) : 0.f;  // clip[-10,10] then [0,1] == [0,1]
      o1 = km ? fminf(fmaxf(x1, -10.f), 10.f) : 0.f;
      o2 = km ? fminf(fmaxf(x2, -10.f), 10.f) : 0.f;
      o3 = km ? fminf(fmaxf(x3, -10.f), 10.f) : 0.f;
      s_v[p] = o0;
      v4f cv; cv.x = o0; cv.y = o1; cv.z = o2; cv.w = scent;
      s_cellv[pp] = cv;
    }
    __syncthreads();

    // ---- E inputs first (earliest waits), then next-A prefetch ----
    const unsigned kc_u = s_kcnt[s & 1];                   // running count
    const uint4 va = ((const uint4*)s_v)[lane];            // 0..255
    const unsigned vb = ((const unsigned*)s_v)[256 + lane];// 256..319 (pads 0)
    if (act) {
      const int q = pp;
      n00 = s_cellv[q-PWD-1]; n01 = s_cellv[q-PWD]; n02 = s_cellv[q-PWD+1];
      n10 = s_cellv[q-1];                           n12 = s_cellv[q+1];
      n20 = s_cellv[q+PWD-1]; n21 = s_cellv[q+PWD]; n22 = s_cellv[q+PWD+1];
    }

    // ---- E (every wave, redundant): warm-probe + full-range radix ----
    // r6 lesson: true kth can be ANY value in [0,1] incl. 0 -> radix spans
    // bits 29..0 from t=0. r11 lesson: probe-bounded accept/reject branches
    // REGRESSED 11% (branch-dense CFG beats ballot savings); keep it simple.
    {
      #define CNT5(cand) ((unsigned)__popcll(__ballot(va.x >= (cand))) \
                        + (unsigned)__popcll(__ballot(va.y >= (cand))) \
                        + (unsigned)__popcll(__ballot(va.z >= (cand))) \
                        + (unsigned)__popcll(__ballot(va.w >= (cand))) \
                        + (unsigned)__popcll(__ballot(vb   >= (cand))))
      int kc = (int)kc_u;
      int k_idx = kc - 1; if (k_idx < 0) k_idx += NPIX;  // torch wrap
      if (k_idx >= NPIX - 1) {
        kth = 0u;                       // keep-all
      } else {
        const unsigned k = (unsigned)(k_idx + 1);
        bool done = false;
        // Warm-start probe: if count_ge(kth_prev) == k, {v>=kth_prev} is an
        // upward-closed set of exactly k values == the top-k set (ties would
        // make the count exceed k). Valid regardless of how kth_prev was
        // obtained. Skip when kth_prev==0 (pads 289..319 would be counted).
        if (kth != 0u) {
          unsigned cp = CNT5(kth);
          if (cp == k) done = true;     // keep kth as-is
        }
        if (!done) {
          unsigned t = 0;
          #pragma unroll 1
          for (int bit = 29; bit >= 0; --bit) {
            unsigned cand = t | (1u << bit);
            unsigned c = CNT5(cand);
            if (c >= k) t = cand;   // largest x with count_ge(x) >= k
            // Early exit: count_ge(cand)==k => exact top-k set. Uniform.
            if (c == k) break;
          }
          kth = t;
        }
      }
      #undef CNT5
      // F (registers only): apply keep to own o0, publish living count
      bool alive = false;
      if (act) {
        if (__float_as_uint(o0) < kth) o0 = 0.f;  // nonneg: uint cmp == float cmp
        alive = o0 > 0.1f;
      }
      unsigned long long m = __ballot(alive);
      if (lane == 0) atomicAdd(&s_kcnt[(s + 1) & 1], (unsigned)__popcll(m));
      // no barrier: next-A uses prefetched regs + reg kth; s_kcnt read in
      // next-E is fenced by barriers b1..b4.
    }
  }

  // ---- outputs: cell | food | total_pixel_val | living_count ----
  if (act) {
    float* oc = out + (size_t)b * (4 * NPIX);
    oc[p] = o0; oc[NPIX + p] = o1; oc[2*NPIX + p] = o2; oc[3*NPIX + p] = o3;
    out[NB*4*NPIX + (size_t)b * NPIX + p] = food_in[(size_t)b * NPIX + p];
  }
  float sv = act ? o0 : 0.f;
  #pragma unroll
  for (int off = 32; off > 0; off >>= 1) sv += __shfl_down(sv, off, 64);
  if (lane == 0) s_sum[wv] = sv;
  __syncthreads();
  if (tid == 0) {
    float tot = 0.f;
    #pragma unroll
    for (int w = 0; w < 8; ++w) tot += s_sum[w];
    out[NB*4*NPIX + NB*NPIX + b]      = tot;
    out[NB*4*NPIX + NB*NPIX + NB + b] = (float)s_kcnt[steps & 1];
  }
}

extern "C" void kernel_launch(void* const* d_in, const int* in_sizes, int n_in,
                              void* d_out, int out_size, void* d_ws, size_t ws_size,
                              hipStream_t stream) {
  (void)in_sizes; (void)n_in; (void)d_ws; (void)ws_size; (void)out_size;
  ca_kernel<<<dim3(NB), dim3(NT), 0, stream>>>(
      (const float*)d_in[0], (const float*)d_in[1], (const int*)d_in[2],
      (const float*)d_in[3], (const float*)d_in[4], (const float*)d_in[5],
      (const float*)d_in[6], (float*)d_out);
}